// Round 4
// baseline (75.592 us; speedup 1.0000x reference)
//
#include <hip/hip_runtime.h>

#define B_Q   8
#define DB    128
#define R_REF 4096
#define S_EDGE 32768
#define NSEG  1024
#define DBITS 1024
#define OUTD  512

typedef __bf16 bf16_t;
typedef bf16_t bf16x8 __attribute__((ext_vector_type(8)));
typedef float  f32x4  __attribute__((ext_vector_type(4)));
typedef unsigned int u32;

__device__ inline unsigned short f2bf(float f){
  unsigned int u = __builtin_bit_cast(unsigned int, f);
  u = (u + 0x7fffu + ((u >> 16) & 1u)) >> 16;
  return (unsigned short)u;
}

__device__ __forceinline__ void gl_lds16(const unsigned short* g, unsigned short* l){
  __builtin_amdgcn_global_load_lds((const __attribute__((address_space(1))) u32*)g,
                                   (__attribute__((address_space(3))) u32*)l, 16, 0, 0);
}

// W (DBITS x OUTD f32) -> WT (OUTD x DBITS bf16), LDS-tiled transpose (coalesced both sides)
__global__ __launch_bounds__(256) void k_wconv(const float* __restrict__ W,
                                               unsigned short* __restrict__ WT){
  __shared__ float tile[64][65];
  const int k0 = blockIdx.x * 64, o0 = blockIdx.y * 64;
  const int tr = threadIdx.x >> 6, tc = threadIdx.x & 63;
  #pragma unroll
  for (int i = 0; i < 16; ++i)
    tile[tr + i*4][tc] = W[(size_t)(k0 + tr + i*4) * OUTD + o0 + tc];
  __syncthreads();
  #pragma unroll
  for (int i = 0; i < 16; ++i)
    WT[(size_t)(o0 + tr + i*4) * DBITS + k0 + tc] = f2bf(tile[tc][tr + i*4]);
}

// refs bytes -> Rb (R x 1024 bf16 of 0/1); 1 byte per thread, contiguous 16B stores
__global__ __launch_bounds__(256) void k_unpack(const int* __restrict__ refs,
                                                unsigned short* __restrict__ Rb){
  int t = blockIdx.x * 256 + threadIdx.x;    // 524288 threads
  int row = t >> 7, byte = t & 127;
  u32 v = (u32)refs[row * DB + byte];
  uint4 o;
  u32* w = (u32*)&o;
  #pragma unroll
  for (int i2 = 0; i2 < 4; ++i2){
    u32 b0 = (v >> (7 - 2*i2)) & 1u;
    u32 b1 = (v >> (6 - 2*i2)) & 1u;
    w[i2] = b0 * 0x3F80u | ((b1 * 0x3F80u) << 16);
  }
  *(uint4*)(Rb + (size_t)row * DBITS + byte * 8) = o;
}

// distsT[r][b] = popc(Q&refs)/popc(Qok&okpos), one wave per (b,r)
__global__ __launch_bounds__(256) void k_dist(const int* __restrict__ Q, const int* __restrict__ Qok,
                                              const int* __restrict__ refs, const int* __restrict__ okpos,
                                              float* __restrict__ distsT){
  int pair = blockIdx.x * 4 + (threadIdx.x >> 6);
  int l = threadIdx.x & 63;
  int b = pair >> 12;
  int r = pair & 4095;
  int q0 = Q[b*DB + l],    q1 = Q[b*DB + 64 + l];
  int a0 = Qok[b*DB + l],  a1 = Qok[b*DB + 64 + l];
  int f0 = refs[r*DB + l], f1 = refs[r*DB + 64 + l];
  int p0 = okpos[r*DB + l],p1 = okpos[r*DB + 64 + l];
  int m = __popc(q0 & f0) + __popc(q1 & f1);
  int o = __popc(a0 & p0) + __popc(a1 & p1);
  int v = m | (o << 16);
  #pragma unroll
  for (int off = 32; off; off >>= 1) v += __shfl_down(v, off);
  if (l == 0) distsT[r * 8 + b] = (float)(v & 0xffff) / (float)(v >> 16);
}

// U[4096][512] f32 = Rb @ WT^T. BM=BN=BK=64, 2-phase dbuf (T3-min), T2 source+read XOR swizzle
__global__ __launch_bounds__(256) void k_ugemm(const unsigned short* __restrict__ Rb,
                                               const unsigned short* __restrict__ WT,
                                               float* __restrict__ U){
  __shared__ unsigned short As[2][64 * 64];
  __shared__ unsigned short Bs[2][64 * 64];
  const int tid = threadIdx.x;
  const int w = tid >> 6, l = tid & 63;
  const int tm = blockIdx.x * 64, tn = blockIdx.y * 64;
  const int wm = (w & 1) * 32, wn = (w >> 1) * 32;
  const int lr = l & 15, kq = l >> 4;

  // staging geometry: thread t, chunk c: row=(t>>3)+c*32, global chunk=(t&7)^(row&7), LDS linear
  const int srow0 = tid >> 3, schunk = tid & 7;
  unsigned short* lA = As[0] + (size_t)tid * 8;   // linear: row*64 + (t&7)*8 == tid*8 (for c=0)
  unsigned short* lB = Bs[0] + (size_t)tid * 8;

  f32x4 acc[2][2] = {};
  int cur = 0;

  #define STAGE(buf, K0)                                                                   \
    do {                                                                                   \
      _Pragma("unroll")                                                                    \
      for (int c = 0; c < 2; ++c){                                                         \
        int row = srow0 + c*32;                                                            \
        int gch = schunk ^ (row & 7);                                                      \
        gl_lds16(Rb + (size_t)(tm + row) * DBITS + (K0) + gch*8,                           \
                 As[buf] + row*64 + schunk*8);                                             \
        gl_lds16(WT + (size_t)(tn + row) * DBITS + (K0) + gch*8,                           \
                 Bs[buf] + row*64 + schunk*8);                                             \
      }                                                                                    \
    } while (0)

  STAGE(0, 0);
  __syncthreads();

  for (int s = 0; s < 16; ++s){
    if (s < 15) STAGE(cur ^ 1, (s + 1) * 64);
    #pragma unroll
    for (int kk = 0; kk < 2; ++kk){
      bf16x8 af[2], bfr[2];
      #pragma unroll
      for (int m = 0; m < 2; ++m){
        int row = wm + m*16 + lr;
        int ch  = (kk*4 + kq) ^ (row & 7);
        af[m] = __builtin_bit_cast(bf16x8, *(const uint4*)(As[cur] + row*64 + ch*8));
      }
      #pragma unroll
      for (int n = 0; n < 2; ++n){
        int row = wn + n*16 + lr;
        int ch  = (kk*4 + kq) ^ (row & 7);
        bfr[n] = __builtin_bit_cast(bf16x8, *(const uint4*)(Bs[cur] + row*64 + ch*8));
      }
      #pragma unroll
      for (int m = 0; m < 2; ++m)
        #pragma unroll
        for (int n = 0; n < 2; ++n)
          acc[m][n] = __builtin_amdgcn_mfma_f32_16x16x32_bf16(af[m], bfr[n], acc[m][n], 0, 0, 0);
    }
    __syncthreads();
    cur ^= 1;
  }
  #undef STAGE

  #pragma unroll
  for (int n = 0; n < 2; ++n)
    #pragma unroll
    for (int m = 0; m < 2; ++m){
      int row = tm + wm + m*16 + kq*4;
      int col = tn + wn + n*16 + lr;
      #pragma unroll
      for (int q = 0; q < 4; ++q)
        U[(size_t)(row + q) * OUTD + col] = acc[m][n][q];
    }
}

// one block per segment, all 8 queries per pass: thread owns 2 cols x 8 batches
__global__ __launch_bounds__(256) void k_scat(const float* __restrict__ distsT,
                                              const int* __restrict__ ref2seg,
                                              const int* __restrict__ segments,
                                              const float* __restrict__ U,
                                              const float* __restrict__ bo,
                                              float* __restrict__ out){
  const int n = blockIdx.x;
  const int t = threadIdx.x;
  const int l = t & 63;

  // lanes even/odd search lower_bound(n)/(n+1), then broadcast
  int tgt = n + (l & 1);
  int lo = 0, hi = S_EDGE;
  #pragma unroll 1
  while (lo < hi){ int mid = (lo + hi) >> 1; if (segments[mid] < tgt) lo = mid + 1; else hi = mid; }
  const int start = __shfl(lo, 0);
  const int end   = __shfl(lo, 1);

  const float b0c = bo[2*t], b1c = bo[2*t + 1];
  float* op = out + (size_t)n * OUTD + 2*t;

  if (start >= end){
    #pragma unroll
    for (int j = 0; j < 8; ++j){ op[(size_t)j * NSEG * OUTD] = b0c; op[(size_t)j * NSEG * OUTD + 1] = b1c; }
    return;
  }

  // online softmax stats for all 8 b: lane = b*8 + slot
  const int sb = l >> 3, es = l & 7;
  float m = -1e30f, s = 0.f;
  for (int e = start + es; e < end; e += 8){
    float d = distsT[ref2seg[e] * 8 + sb];
    float mn = fmaxf(m, d);
    s = s * __expf(m - mn) + __expf(d - mn);
    m = mn;
  }
  #pragma unroll
  for (int msk = 1; msk < 8; msk <<= 1){
    float mo = __shfl_xor(m, msk), so = __shfl_xor(s, msk);
    float mn = fmaxf(m, mo);
    s = s * __expf(m - mn) + so * __expf(mo - mn);
    m = mn;
  }
  float mb[8], ib[8];
  #pragma unroll
  for (int j = 0; j < 8; ++j){
    mb[j] = __shfl(m, j * 8);
    ib[j] = 1.0f / __shfl(s, j * 8);
  }

  float acc[8][2];
  #pragma unroll
  for (int j = 0; j < 8; ++j){ acc[j][0] = 0.f; acc[j][1] = 0.f; }

  int e = start;
  int r = ref2seg[e];
  while (e < end){
    int rn = (e + 1 < end) ? ref2seg[e + 1] : 0;
    float4 d0 = *(const float4*)(distsT + r * 8);
    float4 d1 = *(const float4*)(distsT + r * 8 + 4);
    float2 u  = *(const float2*)(U + ((size_t)r << 9) + 2*t);
    float ds[8] = {d0.x, d0.y, d0.z, d0.w, d1.x, d1.y, d1.z, d1.w};
    #pragma unroll
    for (int j = 0; j < 8; ++j){
      float sc = __expf(ds[j] - mb[j]);
      acc[j][0] += sc * u.x;
      acc[j][1] += sc * u.y;
    }
    r = rn; ++e;
  }

  #pragma unroll
  for (int j = 0; j < 8; ++j){
    op[(size_t)j * NSEG * OUTD]     = acc[j][0] * ib[j] + b0c;
    op[(size_t)j * NSEG * OUTD + 1] = acc[j][1] * ib[j] + b1c;
  }
}

extern "C" void kernel_launch(void* const* d_in, const int* in_sizes, int n_in,
                              void* d_out, int out_size, void* d_ws, size_t ws_size,
                              hipStream_t stream) {
  const int*   Q        = (const int*)d_in[0];
  const int*   Qok      = (const int*)d_in[1];
  const int*   refs     = (const int*)d_in[2];
  const int*   okpos    = (const int*)d_in[3];
  const int*   ref2seg  = (const int*)d_in[4];
  const int*   segments = (const int*)d_in[5];
  const float* W        = (const float*)d_in[7];
  const float* bo       = (const float*)d_in[8];
  float* out = (float*)d_out;

  char* ws = (char*)d_ws;
  unsigned short* WT     = (unsigned short*)ws;                   // [0, 1MB)
  float*          distsT = (float*)(ws + (1u<<20));               // 128 KB
  unsigned short* Rb     = (unsigned short*)(ws + (2u<<20));      // [2MB, 10MB)
  float*          U      = (float*)(ws + (10u<<20));              // [10MB, 18MB)

  k_wconv <<<dim3(DBITS/64, OUTD/64), 256, 0, stream>>>(W, WT);
  k_unpack<<<(R_REF*DB)/256, 256, 0, stream>>>(refs, Rb);
  k_dist  <<<(B_Q*R_REF)/4, 256, 0, stream>>>(Q, Qok, refs, okpos, distsT);
  k_ugemm <<<dim3(R_REF/64, OUTD/64), 256, 0, stream>>>(Rb, WT, U);
  k_scat  <<<NSEG, 256, 0, stream>>>(distsT, ref2seg, segments, U, bo, out);
}

// Round 5
// 60.968 us; speedup vs baseline: 1.2399x; 1.2399x over previous
//
#include <hip/hip_runtime.h>

#define B_Q   8
#define DB    128
#define R_REF 4096
#define S_EDGE 32768
#define NSEG  1024
#define DBITS 1024
#define OUTD  512

typedef __bf16 bf16_t;
typedef bf16_t bf16x8 __attribute__((ext_vector_type(8)));
typedef float  f32x4  __attribute__((ext_vector_type(4)));
typedef unsigned int u32;

__device__ inline unsigned short f2bf(float f){
  unsigned int u = __builtin_bit_cast(unsigned int, f);
  u = (u + 0x7fffu + ((u >> 16) & 1u)) >> 16;
  return (unsigned short)u;
}

__device__ __forceinline__ void gl_lds16(const unsigned short* g, unsigned short* l){
  __builtin_amdgcn_global_load_lds((const __attribute__((address_space(1))) u32*)g,
                                   (__attribute__((address_space(3))) u32*)l, 16, 0, 0);
}

// W (DBITS x OUTD f32) -> WT (OUTD x DBITS bf16), LDS-tiled transpose
__global__ __launch_bounds__(256) void k_wconv(const float* __restrict__ W,
                                               unsigned short* __restrict__ WT){
  __shared__ float tile[64][65];
  const int k0 = blockIdx.x * 64, o0 = blockIdx.y * 64;
  const int tr = threadIdx.x >> 6, tc = threadIdx.x & 63;
  #pragma unroll
  for (int i = 0; i < 16; ++i)
    tile[tr + i*4][tc] = W[(size_t)(k0 + tr + i*4) * OUTD + o0 + tc];
  __syncthreads();
  #pragma unroll
  for (int i = 0; i < 16; ++i)
    WT[(size_t)(o0 + tr + i*4) * DBITS + k0 + tc] = f2bf(tile[tc][tr + i*4]);
}

// refs bytes -> Rb (R x 1024 bf16 of 0/1); 1 byte per thread, contiguous 16B stores
__global__ __launch_bounds__(256) void k_unpack(const int* __restrict__ refs,
                                                unsigned short* __restrict__ Rb){
  int t = blockIdx.x * 256 + threadIdx.x;
  int row = t >> 7, byte = t & 127;
  u32 v = (u32)refs[row * DB + byte];
  uint4 o;
  u32* w = (u32*)&o;
  #pragma unroll
  for (int i2 = 0; i2 < 4; ++i2){
    u32 b0 = (v >> (7 - 2*i2)) & 1u;
    u32 b1 = (v >> (6 - 2*i2)) & 1u;
    w[i2] = b0 * 0x3F80u | ((b1 * 0x3F80u) << 16);
  }
  *(uint4*)(Rb + (size_t)row * DBITS + byte * 8) = o;
}

// distsT[r][b] = popc(Q&refs)/popc(Qok&okpos), one wave per (b,r)
__global__ __launch_bounds__(256) void k_dist(const int* __restrict__ Q, const int* __restrict__ Qok,
                                              const int* __restrict__ refs, const int* __restrict__ okpos,
                                              float* __restrict__ distsT){
  int pair = blockIdx.x * 4 + (threadIdx.x >> 6);
  int l = threadIdx.x & 63;
  int b = pair >> 12;
  int r = pair & 4095;
  int q0 = Q[b*DB + l],    q1 = Q[b*DB + 64 + l];
  int a0 = Qok[b*DB + l],  a1 = Qok[b*DB + 64 + l];
  int f0 = refs[r*DB + l], f1 = refs[r*DB + 64 + l];
  int p0 = okpos[r*DB + l],p1 = okpos[r*DB + 64 + l];
  int m = __popc(q0 & f0) + __popc(q1 & f1);
  int o = __popc(a0 & p0) + __popc(a1 & p1);
  int v = m | (o << 16);
  #pragma unroll
  for (int off = 32; off; off >>= 1) v += __shfl_down(v, off);
  if (l == 0) distsT[r * 8 + b] = (float)(v & 0xffff) / (float)(v >> 16);
}

// per-segment softmax stats for all 8 b: mb/ib[n*8+b], plus segstart[n]
__global__ __launch_bounds__(64) void k_stats(const float* __restrict__ distsT,
                                              const int* __restrict__ ref2seg,
                                              const int* __restrict__ segments,
                                              int* __restrict__ segstart,
                                              float* __restrict__ mb,
                                              float* __restrict__ ib){
  const int n = blockIdx.x;
  const int l = threadIdx.x;
  int tgt = n + (l & 1);
  int lo = 0, hi = S_EDGE;
  #pragma unroll 1
  while (lo < hi){ int mid = (lo + hi) >> 1; if (segments[mid] < tgt) lo = mid + 1; else hi = mid; }
  const int start = __shfl(lo, 0);
  const int end   = __shfl(lo, 1);
  if (l == 0) segstart[n] = start;
  if (n == 0 && l == 1) segstart[NSEG] = S_EDGE;

  const int sb = l >> 3, es = l & 7;
  float m = -1e30f, s = 0.f;
  for (int e = start + es; e < end; e += 8){
    float d = distsT[ref2seg[e] * 8 + sb];
    float mn = fmaxf(m, d);
    s = s * __expf(m - mn) + __expf(d - mn);
    m = mn;
  }
  #pragma unroll
  for (int msk = 1; msk < 8; msk <<= 1){
    float mo = __shfl_xor(m, msk), so = __shfl_xor(s, msk);
    float mn = fmaxf(m, mo);
    s = s * __expf(m - mn) + so * __expf(mo - mn);
    m = mn;
  }
  if (es == 0){
    mb[n*8 + sb] = m;
    ib[n*8 + sb] = (end > start) ? 1.0f / s : 0.f;
  }
}

// sc[e*8+b] = exp(d - m) * inv_s   (1 exp per thread, coalesced)
__global__ __launch_bounds__(256) void k_score(const float* __restrict__ distsT,
                                               const int* __restrict__ ref2seg,
                                               const int* __restrict__ segments,
                                               const float* __restrict__ mb,
                                               const float* __restrict__ ib,
                                               float* __restrict__ sc){
  int t = blockIdx.x * 256 + threadIdx.x;   // S_EDGE*8
  int e = t >> 3, b = t & 7;
  int r = ref2seg[e];
  int n = segments[e];
  sc[t] = __expf(distsT[r*8 + b] - mb[n*8 + b]) * ib[n*8 + b];
}

// U[4096][512] f32 = Rb @ WT^T. 64^2 tile, 2-phase dbuf, T2 source+read XOR swizzle
__global__ __launch_bounds__(256) void k_ugemm(const unsigned short* __restrict__ Rb,
                                               const unsigned short* __restrict__ WT,
                                               float* __restrict__ U){
  __shared__ unsigned short As[2][64 * 64];
  __shared__ unsigned short Bs[2][64 * 64];
  const int tid = threadIdx.x;
  const int w = tid >> 6, l = tid & 63;
  const int tm = blockIdx.x * 64, tn = blockIdx.y * 64;
  const int wm = (w & 1) * 32, wn = (w >> 1) * 32;
  const int lr = l & 15, kq = l >> 4;
  const int srow0 = tid >> 3, schunk = tid & 7;

  f32x4 acc[2][2] = {};
  int cur = 0;

  #define STAGE(buf, K0)                                                                   \
    do {                                                                                   \
      _Pragma("unroll")                                                                    \
      for (int c = 0; c < 2; ++c){                                                         \
        int row = srow0 + c*32;                                                            \
        int gch = schunk ^ (row & 7);                                                      \
        gl_lds16(Rb + (size_t)(tm + row) * DBITS + (K0) + gch*8,                           \
                 As[buf] + row*64 + schunk*8);                                             \
        gl_lds16(WT + (size_t)(tn + row) * DBITS + (K0) + gch*8,                           \
                 Bs[buf] + row*64 + schunk*8);                                             \
      }                                                                                    \
    } while (0)

  STAGE(0, 0);
  __syncthreads();

  for (int s = 0; s < 16; ++s){
    if (s < 15) STAGE(cur ^ 1, (s + 1) * 64);
    #pragma unroll
    for (int kk = 0; kk < 2; ++kk){
      bf16x8 af[2], bfr[2];
      #pragma unroll
      for (int m = 0; m < 2; ++m){
        int row = wm + m*16 + lr;
        int ch  = (kk*4 + kq) ^ (row & 7);
        af[m] = __builtin_bit_cast(bf16x8, *(const uint4*)(As[cur] + row*64 + ch*8));
      }
      #pragma unroll
      for (int n = 0; n < 2; ++n){
        int row = wn + n*16 + lr;
        int ch  = (kk*4 + kq) ^ (row & 7);
        bfr[n] = __builtin_bit_cast(bf16x8, *(const uint4*)(Bs[cur] + row*64 + ch*8));
      }
      #pragma unroll
      for (int m = 0; m < 2; ++m)
        #pragma unroll
        for (int n = 0; n < 2; ++n)
          acc[m][n] = __builtin_amdgcn_mfma_f32_16x16x32_bf16(af[m], bfr[n], acc[m][n], 0, 0, 0);
    }
    __syncthreads();
    cur ^= 1;
  }
  #undef STAGE

  #pragma unroll
  for (int n = 0; n < 2; ++n)
    #pragma unroll
    for (int m = 0; m < 2; ++m){
      int row = tm + wm + m*16 + kq*4;
      int col = tn + wn + n*16 + lr;
      #pragma unroll
      for (int q = 0; q < 4; ++q)
        U[(size_t)(row + q) * OUTD + col] = acc[m][n][q];
    }
}

// one block per segment: thread owns 2 cols x 8 batches; no exp in the loop
__global__ __launch_bounds__(256) void k_scat(const int* __restrict__ ref2seg,
                                              const int* __restrict__ segstart,
                                              const float* __restrict__ sc,
                                              const float* __restrict__ U,
                                              const float* __restrict__ bo,
                                              float* __restrict__ out){
  const int n = blockIdx.x;
  const int t = threadIdx.x;
  const int start = segstart[n], end = segstart[n + 1];
  const float b0c = bo[2*t], b1c = bo[2*t + 1];
  float* op = out + (size_t)n * OUTD + 2*t;

  float acc[8][2];
  #pragma unroll
  for (int j = 0; j < 8; ++j){ acc[j][0] = 0.f; acc[j][1] = 0.f; }

  #pragma unroll 2
  for (int e = start; e < end; ++e){
    int r = ref2seg[e];
    float4 s0 = *(const float4*)(sc + e*8);
    float4 s1 = *(const float4*)(sc + e*8 + 4);
    float2 u  = *(const float2*)(U + ((size_t)r << 9) + 2*t);
    float ss[8] = {s0.x, s0.y, s0.z, s0.w, s1.x, s1.y, s1.z, s1.w};
    #pragma unroll
    for (int j = 0; j < 8; ++j){
      acc[j][0] += ss[j] * u.x;
      acc[j][1] += ss[j] * u.y;
    }
  }

  #pragma unroll
  for (int j = 0; j < 8; ++j){
    op[(size_t)j * NSEG * OUTD]     = acc[j][0] + b0c;
    op[(size_t)j * NSEG * OUTD + 1] = acc[j][1] + b1c;
  }
}

extern "C" void kernel_launch(void* const* d_in, const int* in_sizes, int n_in,
                              void* d_out, int out_size, void* d_ws, size_t ws_size,
                              hipStream_t stream) {
  const int*   Q        = (const int*)d_in[0];
  const int*   Qok      = (const int*)d_in[1];
  const int*   refs     = (const int*)d_in[2];
  const int*   okpos    = (const int*)d_in[3];
  const int*   ref2seg  = (const int*)d_in[4];
  const int*   segments = (const int*)d_in[5];
  const float* W        = (const float*)d_in[7];
  const float* bo       = (const float*)d_in[8];
  float* out = (float*)d_out;

  char* ws = (char*)d_ws;
  unsigned short* WT       = (unsigned short*)ws;                       // [0, 1M)
  float*          distsT   = (float*)(ws + (1u<<20));                   // 128 KB
  int*            segstart = (int*)(ws + (1u<<20) + (128u<<10));        // 4+ KB
  float*          mb       = (float*)(ws + (1u<<20) + (192u<<10));      // 32 KB
  float*          ib       = (float*)(ws + (1u<<20) + (224u<<10));      // 32 KB
  float*          sc       = (float*)(ws + (2u<<20));                   // [2M, 3M)
  unsigned short* Rb       = (unsigned short*)(ws + (3u<<20));          // [3M, 11M)
  float*          U        = (float*)(ws + (11u<<20));                  // [11M, 19M)

  k_wconv <<<dim3(DBITS/64, OUTD/64), 256, 0, stream>>>(W, WT);
  k_unpack<<<(R_REF*DB)/256, 256, 0, stream>>>(refs, Rb);
  k_dist  <<<(B_Q*R_REF)/4, 256, 0, stream>>>(Q, Qok, refs, okpos, distsT);
  k_stats <<<NSEG, 64, 0, stream>>>(distsT, ref2seg, segments, segstart, mb, ib);
  k_score <<<(S_EDGE*8)/256, 256, 0, stream>>>(distsT, ref2seg, segments, mb, ib, sc);
  k_ugemm <<<dim3(R_REF/64, OUTD/64), 256, 0, stream>>>(Rb, WT, U);
  k_scat  <<<NSEG, 256, 0, stream>>>(ref2seg, segstart, sc, U, bo, out);
}

// Round 6
// 50.285 us; speedup vs baseline: 1.5033x; 1.2124x over previous
//
#include <hip/hip_runtime.h>

#define B_Q   8
#define DB    128
#define R_REF 4096
#define S_EDGE 32768
#define NSEG  1024
#define DBITS 1024
#define OUTD  512

#define NB_WCONV 128
#define NB_UNPACK 2048
#define NB_DIST 8192
#define TILE_E 256

typedef __bf16 bf16_t;
typedef bf16_t bf16x8 __attribute__((ext_vector_type(8)));
typedef float  f32x4  __attribute__((ext_vector_type(4)));
typedef unsigned int u32;

__device__ inline unsigned short f2bf(float f){
  unsigned int u = __builtin_bit_cast(unsigned int, f);
  u = (u + 0x7fffu + ((u >> 16) & 1u)) >> 16;
  return (unsigned short)u;
}

__device__ __forceinline__ void gl_lds16(const unsigned short* g, unsigned short* l){
  __builtin_amdgcn_global_load_lds((const __attribute__((address_space(1))) u32*)g,
                                   (__attribute__((address_space(3))) u32*)l, 16, 0, 0);
}

// Fused prep: [0,128) W transpose->bf16 | [128,2176) bit unpack | [2176,10368) dists
__global__ __launch_bounds__(256) void k_prep(const float* __restrict__ W,
                                              unsigned short* __restrict__ WT,
                                              const int* __restrict__ refs,
                                              unsigned short* __restrict__ Rb,
                                              const int* __restrict__ Q,
                                              const int* __restrict__ Qok,
                                              const int* __restrict__ okpos,
                                              float* __restrict__ distsT){
  __shared__ float tile[64][65];
  const int bid = blockIdx.x;
  const int tid = threadIdx.x;

  if (bid < NB_WCONV){
    const int k0 = (bid & 15) * 64, o0 = (bid >> 4) * 64;
    const int tr = tid >> 6, tc = tid & 63;
    #pragma unroll
    for (int i = 0; i < 16; ++i)
      tile[tr + i*4][tc] = W[(size_t)(k0 + tr + i*4) * OUTD + o0 + tc];
    __syncthreads();
    #pragma unroll
    for (int i = 0; i < 16; ++i)
      WT[(size_t)(o0 + tr + i*4) * DBITS + k0 + tc] = f2bf(tile[tc][tr + i*4]);
  } else if (bid < NB_WCONV + NB_UNPACK){
    int t = (bid - NB_WCONV) * 256 + tid;
    int row = t >> 7, byte = t & 127;
    u32 v = (u32)refs[row * DB + byte];
    uint4 o;
    u32* w = (u32*)&o;
    #pragma unroll
    for (int i2 = 0; i2 < 4; ++i2){
      u32 b0 = (v >> (7 - 2*i2)) & 1u;
      u32 b1 = (v >> (6 - 2*i2)) & 1u;
      w[i2] = b0 * 0x3F80u | ((b1 * 0x3F80u) << 16);
    }
    *(uint4*)(Rb + (size_t)row * DBITS + byte * 8) = o;
  } else {
    int pair = (bid - NB_WCONV - NB_UNPACK) * 4 + (tid >> 6);
    int l = tid & 63;
    int b = pair >> 12;
    int r = pair & 4095;
    int q0 = Q[b*DB + l],    q1 = Q[b*DB + 64 + l];
    int a0 = Qok[b*DB + l],  a1 = Qok[b*DB + 64 + l];
    int f0 = refs[r*DB + l], f1 = refs[r*DB + 64 + l];
    int p0 = okpos[r*DB + l],p1 = okpos[r*DB + 64 + l];
    int m = __popc(q0 & f0) + __popc(q1 & f1);
    int o = __popc(a0 & p0) + __popc(a1 & p1);
    int v = m | (o << 16);
    #pragma unroll
    for (int off = 32; off; off >>= 1) v += __shfl_down(v, off);
    if (l == 0) distsT[r * 8 + b] = (float)(v & 0xffff) / (float)(v >> 16);
  }
}

// U[4096][512] f32 = Rb @ WT^T. 64^2 tile, 2-phase dbuf, T2 source+read XOR swizzle
__global__ __launch_bounds__(256) void k_ugemm(const unsigned short* __restrict__ Rb,
                                               const unsigned short* __restrict__ WT,
                                               float* __restrict__ U){
  __shared__ unsigned short As[2][64 * 64];
  __shared__ unsigned short Bs[2][64 * 64];
  const int tid = threadIdx.x;
  const int w = tid >> 6, l = tid & 63;
  const int tm = blockIdx.x * 64, tn = blockIdx.y * 64;
  const int wm = (w & 1) * 32, wn = (w >> 1) * 32;
  const int lr = l & 15, kq = l >> 4;
  const int srow0 = tid >> 3, schunk = tid & 7;

  f32x4 acc[2][2] = {};
  int cur = 0;

  #define STAGE(buf, K0)                                                                   \
    do {                                                                                   \
      _Pragma("unroll")                                                                    \
      for (int c = 0; c < 2; ++c){                                                         \
        int row = srow0 + c*32;                                                            \
        int gch = schunk ^ (row & 7);                                                      \
        gl_lds16(Rb + (size_t)(tm + row) * DBITS + (K0) + gch*8,                           \
                 As[buf] + row*64 + schunk*8);                                             \
        gl_lds16(WT + (size_t)(tn + row) * DBITS + (K0) + gch*8,                           \
                 Bs[buf] + row*64 + schunk*8);                                             \
      }                                                                                    \
    } while (0)

  STAGE(0, 0);
  __syncthreads();

  for (int s = 0; s < 16; ++s){
    if (s < 15) STAGE(cur ^ 1, (s + 1) * 64);
    #pragma unroll
    for (int kk = 0; kk < 2; ++kk){
      bf16x8 af[2], bfr[2];
      #pragma unroll
      for (int m = 0; m < 2; ++m){
        int row = wm + m*16 + lr;
        int ch  = (kk*4 + kq) ^ (row & 7);
        af[m] = __builtin_bit_cast(bf16x8, *(const uint4*)(As[cur] + row*64 + ch*8));
      }
      #pragma unroll
      for (int n = 0; n < 2; ++n){
        int row = wn + n*16 + lr;
        int ch  = (kk*4 + kq) ^ (row & 7);
        bfr[n] = __builtin_bit_cast(bf16x8, *(const uint4*)(Bs[cur] + row*64 + ch*8));
      }
      #pragma unroll
      for (int m = 0; m < 2; ++m)
        #pragma unroll
        for (int n = 0; n < 2; ++n)
          acc[m][n] = __builtin_amdgcn_mfma_f32_16x16x32_bf16(af[m], bfr[n], acc[m][n], 0, 0, 0);
    }
    __syncthreads();
    cur ^= 1;
  }
  #undef STAGE

  #pragma unroll
  for (int n = 0; n < 2; ++n)
    #pragma unroll
    for (int m = 0; m < 2; ++m){
      int row = tm + wm + m*16 + kq*4;
      int col = tn + wn + n*16 + lr;
      #pragma unroll
      for (int q = 0; q < 4; ++q)
        U[(size_t)(row + q) * OUTD + col] = acc[m][n][q];
    }
}

// Fused per-segment: search + stats (wave0) + score->LDS + scatter-FMA.
// Thread owns 2 cols x 8 batches; zero transcendentals in the FMA loop.
__global__ __launch_bounds__(256) void k_scat(const float* __restrict__ distsT,
                                              const int* __restrict__ ref2seg,
                                              const int* __restrict__ segments,
                                              const float* __restrict__ U,
                                              const float* __restrict__ bo,
                                              float* __restrict__ out){
  __shared__ float mbs[8], ibs[8];
  __shared__ float scl[TILE_E * 8];
  __shared__ int   rix[TILE_E];
  const int n = blockIdx.x;
  const int t = threadIdx.x;
  const int l = t & 63;

  // even/odd lanes search lower_bound(n)/(n+1); every wave does it redundantly
  int tgt = n + (l & 1);
  int lo = 0, hi = S_EDGE;
  #pragma unroll 1
  while (lo < hi){ int mid = (lo + hi) >> 1; if (segments[mid] < tgt) lo = mid + 1; else hi = mid; }
  const int start = __shfl(lo, 0);
  const int end   = __shfl(lo, 1);

  const float b0c = bo[2*t], b1c = bo[2*t + 1];
  float* op = out + (size_t)n * OUTD + 2*t;

  if (start >= end){
    #pragma unroll
    for (int j = 0; j < 8; ++j){ op[(size_t)j * NSEG * OUTD] = b0c; op[(size_t)j * NSEG * OUTD + 1] = b1c; }
    return;
  }

  // stats on wave 0: lane = sb*8 + es; online softmax per batch sb
  if (t < 64){
    const int sb = t >> 3, es = t & 7;
    float m = -1e30f, s = 0.f;
    for (int e = start + es; e < end; e += 8){
      float d = distsT[ref2seg[e] * 8 + sb];
      float mn = fmaxf(m, d);
      s = s * __expf(m - mn) + __expf(d - mn);
      m = mn;
    }
    #pragma unroll
    for (int msk = 1; msk < 8; msk <<= 1){
      float mo = __shfl_xor(m, msk), so = __shfl_xor(s, msk);
      float mn = fmaxf(m, mo);
      s = s * __expf(m - mn) + so * __expf(mo - mn);
      m = mn;
    }
    if (es == 0){ mbs[sb] = m; ibs[sb] = 1.0f / s; }
  }
  __syncthreads();

  float acc[8][2];
  #pragma unroll
  for (int j = 0; j < 8; ++j){ acc[j][0] = 0.f; acc[j][1] = 0.f; }

  for (int e0 = start; e0 < end; e0 += TILE_E){
    const int cnt = min(TILE_E, end - e0);
    // score phase: 1 exp per thread-slot, coalesced-ish gathers
    for (int i = t; i < cnt * 8; i += 256){
      int e = e0 + (i >> 3), b = i & 7;
      int r = ref2seg[e];
      if (b == 0) rix[i >> 3] = r;
      scl[i] = __expf(distsT[r*8 + b] - mbs[b]) * ibs[b];
    }
    __syncthreads();

    #pragma unroll 2
    for (int e = 0; e < cnt; ++e){
      int r = rix[e];
      float4 s0 = *(const float4*)(scl + e*8);
      float4 s1 = *(const float4*)(scl + e*8 + 4);
      float2 u  = *(const float2*)(U + ((size_t)r << 9) + 2*t);
      float ss[8] = {s0.x, s0.y, s0.z, s0.w, s1.x, s1.y, s1.z, s1.w};
      #pragma unroll
      for (int j = 0; j < 8; ++j){
        acc[j][0] += ss[j] * u.x;
        acc[j][1] += ss[j] * u.y;
      }
    }
    __syncthreads();
  }

  #pragma unroll
  for (int j = 0; j < 8; ++j){
    op[(size_t)j * NSEG * OUTD]     = acc[j][0] + b0c;
    op[(size_t)j * NSEG * OUTD + 1] = acc[j][1] + b1c;
  }
}

extern "C" void kernel_launch(void* const* d_in, const int* in_sizes, int n_in,
                              void* d_out, int out_size, void* d_ws, size_t ws_size,
                              hipStream_t stream) {
  const int*   Q        = (const int*)d_in[0];
  const int*   Qok      = (const int*)d_in[1];
  const int*   refs     = (const int*)d_in[2];
  const int*   okpos    = (const int*)d_in[3];
  const int*   ref2seg  = (const int*)d_in[4];
  const int*   segments = (const int*)d_in[5];
  const float* W        = (const float*)d_in[7];
  const float* bo       = (const float*)d_in[8];
  float* out = (float*)d_out;

  char* ws = (char*)d_ws;
  unsigned short* WT     = (unsigned short*)ws;                   // [0, 1M)
  float*          distsT = (float*)(ws + (1u<<20));               // 128 KB
  unsigned short* Rb     = (unsigned short*)(ws + (2u<<20));      // [2M, 10M)
  float*          U      = (float*)(ws + (11u<<20));              // [11M, 19M)

  k_prep <<<NB_WCONV + NB_UNPACK + NB_DIST, 256, 0, stream>>>(W, WT, refs, Rb, Q, Qok, okpos, distsT);
  k_ugemm<<<dim3(R_REF/64, OUTD/64), 256, 0, stream>>>(Rb, WT, U);
  k_scat <<<NSEG, 256, 0, stream>>>(distsT, ref2seg, segments, U, bo, out);
}

// Round 7
// 43.190 us; speedup vs baseline: 1.7502x; 1.1643x over previous
//
#include <hip/hip_runtime.h>

#define B_Q   8
#define DB    128
#define R_REF 4096
#define S_EDGE 32768
#define NSEG  1024
#define DBITS 1024
#define OUTD  512

#define NB_WCONV 128
#define NB_UNPACK 2048
#define NB_DIST 8192
#define TILE_E 256

typedef __bf16 bf16_t;
typedef bf16_t bf16x8 __attribute__((ext_vector_type(8)));
typedef float  f32x4  __attribute__((ext_vector_type(4)));
typedef unsigned int u32;

__device__ inline unsigned short f2bf(float f){
  unsigned int u = __builtin_bit_cast(unsigned int, f);
  u = (u + 0x7fffu + ((u >> 16) & 1u)) >> 16;
  return (unsigned short)u;
}

__device__ __forceinline__ void gl_lds16(const unsigned short* g, unsigned short* l){
  __builtin_amdgcn_global_load_lds((const __attribute__((address_space(1))) u32*)g,
                                   (__attribute__((address_space(3))) u32*)l, 16, 0, 0);
}

// Fused prep: [0,128) W transpose->bf16 | [128,2176) bit unpack | [2176,10368) dists
__global__ __launch_bounds__(256) void k_prep(const float* __restrict__ W,
                                              unsigned short* __restrict__ WT,
                                              const int* __restrict__ refs,
                                              unsigned short* __restrict__ Rb,
                                              const int* __restrict__ Q,
                                              const int* __restrict__ Qok,
                                              const int* __restrict__ okpos,
                                              float* __restrict__ distsT){
  __shared__ float tile[64][65];
  const int bid = blockIdx.x;
  const int tid = threadIdx.x;

  if (bid < NB_WCONV){
    const int k0 = (bid & 15) * 64, o0 = (bid >> 4) * 64;
    const int tr = tid >> 6, tc = tid & 63;
    #pragma unroll
    for (int i = 0; i < 16; ++i)
      tile[tr + i*4][tc] = W[(size_t)(k0 + tr + i*4) * OUTD + o0 + tc];
    __syncthreads();
    #pragma unroll
    for (int i = 0; i < 16; ++i)
      WT[(size_t)(o0 + tr + i*4) * DBITS + k0 + tc] = f2bf(tile[tc][tr + i*4]);
  } else if (bid < NB_WCONV + NB_UNPACK){
    int t = (bid - NB_WCONV) * 256 + tid;
    int row = t >> 7, byte = t & 127;
    u32 v = (u32)refs[row * DB + byte];
    uint4 o;
    u32* w = (u32*)&o;
    #pragma unroll
    for (int i2 = 0; i2 < 4; ++i2){
      u32 b0 = (v >> (7 - 2*i2)) & 1u;
      u32 b1 = (v >> (6 - 2*i2)) & 1u;
      w[i2] = b0 * 0x3F80u | ((b1 * 0x3F80u) << 16);
    }
    *(uint4*)(Rb + (size_t)row * DBITS + byte * 8) = o;
  } else {
    int pair = (bid - NB_WCONV - NB_UNPACK) * 4 + (tid >> 6);
    int l = tid & 63;
    int b = pair >> 12;
    int r = pair & 4095;
    int q0 = Q[b*DB + l],    q1 = Q[b*DB + 64 + l];
    int a0 = Qok[b*DB + l],  a1 = Qok[b*DB + 64 + l];
    int f0 = refs[r*DB + l], f1 = refs[r*DB + 64 + l];
    int p0 = okpos[r*DB + l],p1 = okpos[r*DB + 64 + l];
    int m = __popc(q0 & f0) + __popc(q1 & f1);
    int o = __popc(a0 & p0) + __popc(a1 & p1);
    int v = m | (o << 16);
    #pragma unroll
    for (int off = 32; off; off >>= 1) v += __shfl_down(v, off);
    if (l == 0) distsT[r * 8 + b] = (float)(v & 0xffff) / (float)(v >> 16);
  }
}

// U[4096][512] bf16 = Rb @ WT^T. 64^2 tile, BK=128, 2-phase dbuf, 16-chunk XOR swizzle
__global__ __launch_bounds__(256) void k_ugemm(const unsigned short* __restrict__ Rb,
                                               const unsigned short* __restrict__ WT,
                                               unsigned short* __restrict__ U){
  __shared__ unsigned short As[2][64 * 128];   // 32 KB
  __shared__ unsigned short Bs[2][64 * 128];   // 32 KB
  const int tid = threadIdx.x;
  const int w = tid >> 6, l = tid & 63;
  const int tm = blockIdx.x * 64, tn = blockIdx.y * 64;
  const int wm = (w & 1) * 32, wn = (w >> 1) * 32;
  const int lr = l & 15, kq = l >> 4;

  f32x4 acc[2][2] = {};
  int cur = 0;

  // 64 rows x 16 chunks(16B) per matrix per K-step; LDS linear (addr = idx*16B),
  // swizzle applied on the GLOBAL source chunk (rule #21), involution ch^(row&15)
  #define STAGE(buf, K0)                                                                   \
    do {                                                                                   \
      _Pragma("unroll")                                                                    \
      for (int c = 0; c < 4; ++c){                                                         \
        int idx = c * 256 + tid;                                                           \
        int row = idx >> 4, ch = idx & 15;                                                 \
        int gch = ch ^ (row & 15);                                                         \
        gl_lds16(Rb + (size_t)(tm + row) * DBITS + (K0) + gch*8,                           \
                 As[buf] + row*128 + ch*8);                                                \
        gl_lds16(WT + (size_t)(tn + row) * DBITS + (K0) + gch*8,                           \
                 Bs[buf] + row*128 + ch*8);                                                \
      }                                                                                    \
    } while (0)

  STAGE(0, 0);
  __syncthreads();

  for (int s = 0; s < 8; ++s){
    if (s < 7) STAGE(cur ^ 1, (s + 1) * 128);
    #pragma unroll
    for (int kk = 0; kk < 4; ++kk){
      bf16x8 af[2], bfr[2];
      #pragma unroll
      for (int m = 0; m < 2; ++m){
        int row = wm + m*16 + lr;
        int ch  = (kk*4 + kq) ^ (row & 15);
        af[m] = __builtin_bit_cast(bf16x8, *(const uint4*)(As[cur] + row*128 + ch*8));
      }
      #pragma unroll
      for (int n = 0; n < 2; ++n){
        int row = wn + n*16 + lr;
        int ch  = (kk*4 + kq) ^ (row & 15);
        bfr[n] = __builtin_bit_cast(bf16x8, *(const uint4*)(Bs[cur] + row*128 + ch*8));
      }
      #pragma unroll
      for (int m = 0; m < 2; ++m)
        #pragma unroll
        for (int n = 0; n < 2; ++n)
          acc[m][n] = __builtin_amdgcn_mfma_f32_16x16x32_bf16(af[m], bfr[n], acc[m][n], 0, 0, 0);
    }
    __syncthreads();
    cur ^= 1;
  }
  #undef STAGE

  #pragma unroll
  for (int n = 0; n < 2; ++n)
    #pragma unroll
    for (int m = 0; m < 2; ++m){
      int row = tm + wm + m*16 + kq*4;
      int col = tn + wn + n*16 + lr;
      #pragma unroll
      for (int q = 0; q < 4; ++q)
        U[(size_t)(row + q) * OUTD + col] = f2bf(acc[m][n][q]);
    }
}

// Fused per-segment: search + stats (wave0) + score->LDS + scatter-FMA (bf16 U).
__global__ __launch_bounds__(256) void k_scat(const float* __restrict__ distsT,
                                              const int* __restrict__ ref2seg,
                                              const int* __restrict__ segments,
                                              const unsigned short* __restrict__ U,
                                              const float* __restrict__ bo,
                                              float* __restrict__ out){
  __shared__ float mbs[8], ibs[8];
  __shared__ float scl[TILE_E * 8];
  __shared__ int   rix[TILE_E];
  const int n = blockIdx.x;
  const int t = threadIdx.x;
  const int l = t & 63;

  int tgt = n + (l & 1);
  int lo = 0, hi = S_EDGE;
  #pragma unroll 1
  while (lo < hi){ int mid = (lo + hi) >> 1; if (segments[mid] < tgt) lo = mid + 1; else hi = mid; }
  const int start = __shfl(lo, 0);
  const int end   = __shfl(lo, 1);

  const float b0c = bo[2*t], b1c = bo[2*t + 1];
  float* op = out + (size_t)n * OUTD + 2*t;

  if (start >= end){
    #pragma unroll
    for (int j = 0; j < 8; ++j){ op[(size_t)j * NSEG * OUTD] = b0c; op[(size_t)j * NSEG * OUTD + 1] = b1c; }
    return;
  }

  if (t < 64){
    const int sb = t >> 3, es = t & 7;
    float m = -1e30f, s = 0.f;
    for (int e = start + es; e < end; e += 8){
      float d = distsT[ref2seg[e] * 8 + sb];
      float mn = fmaxf(m, d);
      s = s * __expf(m - mn) + __expf(d - mn);
      m = mn;
    }
    #pragma unroll
    for (int msk = 1; msk < 8; msk <<= 1){
      float mo = __shfl_xor(m, msk), so = __shfl_xor(s, msk);
      float mn = fmaxf(m, mo);
      s = s * __expf(m - mn) + so * __expf(mo - mn);
      m = mn;
    }
    if (es == 0){ mbs[sb] = m; ibs[sb] = 1.0f / s; }
  }
  __syncthreads();

  float acc[8][2];
  #pragma unroll
  for (int j = 0; j < 8; ++j){ acc[j][0] = 0.f; acc[j][1] = 0.f; }

  for (int e0 = start; e0 < end; e0 += TILE_E){
    const int cnt = min(TILE_E, end - e0);
    for (int i = t; i < cnt * 8; i += 256){
      int e = e0 + (i >> 3), b = i & 7;
      int r = ref2seg[e];
      if (b == 0) rix[i >> 3] = r;
      scl[i] = __expf(distsT[r*8 + b] - mbs[b]) * ibs[b];
    }
    __syncthreads();

    #pragma unroll 4
    for (int e = 0; e < cnt; ++e){
      int r = rix[e];
      float4 s0 = *(const float4*)(scl + e*8);
      float4 s1 = *(const float4*)(scl + e*8 + 4);
      u32 uu = *(const u32*)(U + ((size_t)r << 9) + 2*t);
      float ux = __builtin_bit_cast(float, uu << 16);
      float uy = __builtin_bit_cast(float, uu & 0xffff0000u);
      float ss[8] = {s0.x, s0.y, s0.z, s0.w, s1.x, s1.y, s1.z, s1.w};
      #pragma unroll
      for (int j = 0; j < 8; ++j){
        acc[j][0] += ss[j] * ux;
        acc[j][1] += ss[j] * uy;
      }
    }
    __syncthreads();
  }

  #pragma unroll
  for (int j = 0; j < 8; ++j){
    op[(size_t)j * NSEG * OUTD]     = acc[j][0] + b0c;
    op[(size_t)j * NSEG * OUTD + 1] = acc[j][1] + b1c;
  }
}

extern "C" void kernel_launch(void* const* d_in, const int* in_sizes, int n_in,
                              void* d_out, int out_size, void* d_ws, size_t ws_size,
                              hipStream_t stream) {
  const int*   Q        = (const int*)d_in[0];
  const int*   Qok      = (const int*)d_in[1];
  const int*   refs     = (const int*)d_in[2];
  const int*   okpos    = (const int*)d_in[3];
  const int*   ref2seg  = (const int*)d_in[4];
  const int*   segments = (const int*)d_in[5];
  const float* W        = (const float*)d_in[7];
  const float* bo       = (const float*)d_in[8];
  float* out = (float*)d_out;

  char* ws = (char*)d_ws;
  unsigned short* WT     = (unsigned short*)ws;                   // [0, 1M)
  float*          distsT = (float*)(ws + (1u<<20));               // 128 KB
  unsigned short* Rb     = (unsigned short*)(ws + (2u<<20));      // [2M, 10M)
  unsigned short* U      = (unsigned short*)(ws + (11u<<20));     // [11M, 15M) bf16

  k_prep <<<NB_WCONV + NB_UNPACK + NB_DIST, 256, 0, stream>>>(W, WT, refs, Rb, Q, Qok, okpos, distsT);
  k_ugemm<<<dim3(R_REF/64, OUTD/64), 256, 0, stream>>>(Rb, WT, U);
  k_scat <<<NSEG, 256, 0, stream>>>(distsT, ref2seg, segments, U, bo, out);
}